// Round 1
// baseline (265.725 us; speedup 1.0000x reference)
//
#include <hip/hip_runtime.h>

#define N_NODES 100000
#define N_EDGES 1000000
#define EPS 1e-5f
#define SLOPE 0.01f
#define NBLK 391   // ceil(N_NODES/256)
#define GBLK 1563  // ceil(N_NODES/64) for gather (5 threads/node, 320/block)

// ---------------------------------------------------------------------------
// ws layout:
//   S        : N*80 floats (32 MB)   per-node aggregated outer products
//   perm_src : E ints     (4 MB)     src node id in CSR(dst) order
//   perm_ef  : E float4   (16 MB)    edge features in CSR(dst) order
//   hist     : N ints     [zeroed] -> in-degree
//   cursor   : N ints     [zeroed] -> scatter cursor per dst
//   stats    : 32 floats  [zeroed]   sum[16], sumsq[16]
//   row_part : N ints
//   bsum     : 512 ints
//   bsum_ex  : 512 ints
// ---------------------------------------------------------------------------

// Kernel 1: in-degree histogram (4 edges/thread, int4 loads).
__global__ __launch_bounds__(256) void count_kernel(
    const int* __restrict__ edge_index,
    int* __restrict__ hist)
{
    int i = blockIdx.x * 256 + threadIdx.x;
    if (i >= N_EDGES / 4) return;
    int4 d = *(const int4*)(edge_index + N_EDGES + i * 4);
    atomicAdd(hist + d.x, 1);
    atomicAdd(hist + d.y, 1);
    atomicAdd(hist + d.z, 1);
    atomicAdd(hist + d.w, 1);
}

// Kernel 2: block-local exclusive scan of hist + block sums.
__global__ __launch_bounds__(256) void scan1_kernel(
    const int* __restrict__ hist,
    int* __restrict__ row_part,
    int* __restrict__ bsum)
{
    __shared__ int s[256];
    int tid = threadIdx.x;
    int idx = blockIdx.x * 256 + tid;
    int val = (idx < N_NODES) ? hist[idx] : 0;
    s[tid] = val;
    __syncthreads();
    #pragma unroll
    for (int off = 1; off < 256; off <<= 1) {
        int t = (tid >= off) ? s[tid - off] : 0;
        __syncthreads();
        s[tid] += t;
        __syncthreads();
    }
    if (idx < N_NODES) row_part[idx] = s[tid] - val;
    if (tid == 255) bsum[blockIdx.x] = s[255];
}

// Kernel 3: exclusive scan of block sums (single block of 512).
__global__ __launch_bounds__(512) void scan2_kernel(
    const int* __restrict__ bsum,
    int* __restrict__ bsum_ex)
{
    __shared__ int s[512];
    int tid = threadIdx.x;
    int val = (tid < NBLK) ? bsum[tid] : 0;
    s[tid] = val;
    __syncthreads();
    #pragma unroll
    for (int off = 1; off < 512; off <<= 1) {
        int t = (tid >= off) ? s[tid - off] : 0;
        __syncthreads();
        s[tid] += t;
        __syncthreads();
    }
    bsum_ex[tid] = s[tid] - val;
}

// ---------------------------------------------------------------------------
// Kernel 4: scatter edge PAYLOAD (src, ef) into CSR(dst) order.
// Sequential reads of src/ef; random 20 B writes per edge (paid once here so
// the gather loop reads everything sequentially). Slot via atomic cursor —
// replaces the old rank_kernel pass entirely.
// ---------------------------------------------------------------------------
__global__ __launch_bounds__(256) void scatter_kernel(
    const float* __restrict__ efeat,
    const int* __restrict__ edge_index,
    const int* __restrict__ row_part,
    const int* __restrict__ bsum_ex,
    int* __restrict__ cursor,
    int* __restrict__ perm_src,
    float4* __restrict__ perm_ef)
{
    int eid = blockIdx.x * 256 + threadIdx.x;
    if (eid >= N_EDGES) return;
    int src = edge_index[eid];
    int dst = edge_index[N_EDGES + eid];
    float4 ef = *(const float4*)(efeat + (size_t)eid * 4);
    int slot = row_part[dst] + bsum_ex[dst >> 8] + atomicAdd(cursor + dst, 1);
    perm_src[slot] = src;
    perm_ef[slot] = ef;
}

// ---------------------------------------------------------------------------
// Kernel 5: S[n] = sum over incoming edges of outer(v[src], [1, ef]).
// 5 threads per node: thread t accumulates component t (16 floats).
// After payload staging, perm_src/perm_ef reads are fully sequential;
// the only random access is v[src] (6.4 MB, L2/L3 resident, 64 B lines).
// ---------------------------------------------------------------------------
__global__ __launch_bounds__(320) void gather_s_kernel(
    const float* __restrict__ v,
    const int* __restrict__ perm_src,
    const float4* __restrict__ perm_ef,
    const int* __restrict__ hist,
    const int* __restrict__ row_part,
    const int* __restrict__ bsum_ex,
    float* __restrict__ S)
{
    int tid = blockIdx.x * 320 + threadIdx.x;
    int n = tid / 5;
    int t = tid % 5;
    if (n >= N_NODES) return;

    int start = row_part[n] + bsum_ex[n >> 8];
    int deg = hist[n];

    float acc[16];
    #pragma unroll
    for (int i = 0; i < 16; ++i) acc[i] = 0.0f;

    for (int j = 0; j < deg; ++j) {
        int src = perm_src[start + j];
        float4 ef = perm_ef[start + j];
        float c = 1.0f;
        c = (t == 1) ? ef.x : c;
        c = (t == 2) ? ef.y : c;
        c = (t == 3) ? ef.z : c;
        c = (t == 4) ? ef.w : c;
        const float* vp = v + (size_t)src * 16;
        #pragma unroll
        for (int i = 0; i < 4; ++i) {
            float4 tv = *(const float4*)(vp + i * 4);
            acc[i*4+0] = fmaf(c, tv.x, acc[i*4+0]);
            acc[i*4+1] = fmaf(c, tv.y, acc[i*4+1]);
            acc[i*4+2] = fmaf(c, tv.z, acc[i*4+2]);
            acc[i*4+3] = fmaf(c, tv.w, acc[i*4+3]);
        }
    }

    float* sp = S + (size_t)n * 80 + t * 16;
    #pragma unroll
    for (int i = 0; i < 4; ++i)
        *(float4*)(sp + i * 4) = make_float4(acc[i*4+0], acc[i*4+1],
                                             acc[i*4+2], acc[i*4+3]);
}

// ---------------------------------------------------------------------------
// Kernel 6: per-node: summed = S0*B + sum_k Sk*Wk; mean + root + bias -> out;
// per-column sum/sumsq reduction into stats. Weights are wave-uniform -> SGPR.
// ---------------------------------------------------------------------------
__global__ __launch_bounds__(256) void node_kernel(
    const float* __restrict__ v,
    const float* __restrict__ S,
    const int* __restrict__ hist,
    const float* __restrict__ enet_w,
    const float* __restrict__ enet_b,
    const float* __restrict__ root,
    const float* __restrict__ bias,
    float* __restrict__ out,
    float* __restrict__ stats)
{
    int n = blockIdx.x * 256 + threadIdx.x;
    bool active = (n < N_NODES);

    float val[16];
    if (active) {
        float s[80];
        #pragma unroll
        for (int i = 0; i < 20; ++i) {
            float4 tv = *(const float4*)(S + (size_t)n * 80 + i * 4);
            s[i*4+0] = tv.x; s[i*4+1] = tv.y; s[i*4+2] = tv.z; s[i*4+3] = tv.w;
        }
        float vn[16];
        #pragma unroll
        for (int i = 0; i < 4; ++i) {
            float4 tv = *(const float4*)(v + (size_t)n * 16 + i * 4);
            vn[i*4+0] = tv.x; vn[i*4+1] = tv.y; vn[i*4+2] = tv.z; vn[i*4+3] = tv.w;
        }
        float scale = 1.0f / fmaxf((float)hist[n], 1.0f);

        #pragma unroll
        for (int o = 0; o < 16; ++o) {
            float a = 0.0f;
            #pragma unroll
            for (int i = 0; i < 16; ++i) {
                a = fmaf(s[i], enet_b[i * 16 + o], a);           // S0 * B
                #pragma unroll
                for (int k = 0; k < 4; ++k)
                    a = fmaf(s[16 + k * 16 + i],
                             enet_w[(i * 16 + o) * 4 + k], a);   // Sk * Wk
            }
            a = fmaf(a, scale, bias[o]);
            #pragma unroll
            for (int i = 0; i < 16; ++i)
                a = fmaf(vn[i], root[i * 16 + o], a);
            val[o] = a;
        }
        #pragma unroll
        for (int i = 0; i < 4; ++i)
            *(float4*)(out + (size_t)n * 16 + i * 4) =
                make_float4(val[i*4+0], val[i*4+1], val[i*4+2], val[i*4+3]);
    } else {
        #pragma unroll
        for (int o = 0; o < 16; ++o) val[o] = 0.0f;
    }

    // wave butterfly + LDS reduction of sum / sumsq per column
    float ssum[16], ssq[16];
    #pragma unroll
    for (int o = 0; o < 16; ++o) {
        float a = val[o];
        float b = a * a;
        #pragma unroll
        for (int m = 1; m < 64; m <<= 1) {
            a += __shfl_xor(a, m, 64);
            b += __shfl_xor(b, m, 64);
        }
        ssum[o] = a; ssq[o] = b;
    }
    __shared__ float part[4][32];
    int wave = threadIdx.x >> 6;
    int lane = threadIdx.x & 63;
    if (lane == 0) {
        #pragma unroll
        for (int o = 0; o < 16; ++o) {
            part[wave][o] = ssum[o];
            part[wave][16 + o] = ssq[o];
        }
    }
    __syncthreads();
    if (threadIdx.x < 32) {
        float t = part[0][threadIdx.x] + part[1][threadIdx.x] +
                  part[2][threadIdx.x] + part[3][threadIdx.x];
        unsafeAtomicAdd(stats + threadIdx.x, t);
    }
}

// Kernel 7: BatchNorm (batch stats) + LeakyReLU, in place, float4-vectorized.
__global__ __launch_bounds__(256) void final_kernel(
    float* __restrict__ out,
    const float* __restrict__ stats,
    const float* __restrict__ gamma,
    const float* __restrict__ beta)
{
    int idx = blockIdx.x * 256 + threadIdx.x;      // float4 index
    if (idx >= N_NODES * 4) return;
    int o0 = (idx & 3) << 2;
    const float invN = 1.0f / (float)N_NODES;
    float4 x = *((const float4*)out + idx);
    float xs[4] = {x.x, x.y, x.z, x.w};
    float r[4];
    #pragma unroll
    for (int u = 0; u < 4; ++u) {
        int o = o0 + u;
        float mu = stats[o] * invN;
        float var = fmaxf(stats[16 + o] * invN - mu * mu, 0.0f);
        float y = fmaf(gamma[o] * (xs[u] - mu), rsqrtf(var + EPS), beta[o]);
        r[u] = (y >= 0.0f) ? y : SLOPE * y;
    }
    *((float4*)out + idx) = make_float4(r[0], r[1], r[2], r[3]);
}

extern "C" void kernel_launch(void* const* d_in, const int* in_sizes, int n_in,
                              void* d_out, int out_size, void* d_ws, size_t ws_size,
                              hipStream_t stream)
{
    const float* v = (const float*)d_in[0];
    const float* e = (const float*)d_in[1];
    const int* edge_index = (const int*)d_in[2];
    const float* enet_w = (const float*)d_in[3];
    const float* enet_b = (const float*)d_in[4];
    const float* root = (const float*)d_in[5];
    const float* bias = (const float*)d_in[6];
    const float* gamma = (const float*)d_in[7];
    const float* beta = (const float*)d_in[8];
    float* out = (float*)d_out;

    char* ws = (char*)d_ws;
    float*  S        = (float*)ws;                  ws += (size_t)N_NODES * 80 * 4;
    int*    perm_src = (int*)ws;                    ws += (size_t)N_EDGES * 4;
    float4* perm_ef  = (float4*)ws;                 ws += (size_t)N_EDGES * 16;
    int*    hist     = (int*)ws;                    ws += (size_t)N_NODES * 4;
    int*    cursor   = (int*)ws;                    ws += (size_t)N_NODES * 4;
    float*  stats    = (float*)ws;                  ws += 32 * 4;
    int*    row_part = (int*)ws;                    ws += (size_t)N_NODES * 4;
    int*    bsum     = (int*)ws;                    ws += 512 * 4;
    int*    bsum_ex  = (int*)ws;

    // zero hist + cursor + stats (contiguous)
    hipMemsetAsync(hist, 0, (size_t)N_NODES * 4 * 2 + 32 * 4, stream);

    count_kernel<<<(N_EDGES / 4 + 255) / 256, 256, 0, stream>>>(edge_index, hist);
    scan1_kernel<<<NBLK, 256, 0, stream>>>(hist, row_part, bsum);
    scan2_kernel<<<1, 512, 0, stream>>>(bsum, bsum_ex);
    scatter_kernel<<<(N_EDGES + 255) / 256, 256, 0, stream>>>(
        e, edge_index, row_part, bsum_ex, cursor, perm_src, perm_ef);
    gather_s_kernel<<<GBLK, 320, 0, stream>>>(
        v, perm_src, perm_ef, hist, row_part, bsum_ex, S);
    node_kernel<<<NBLK, 256, 0, stream>>>(
        v, S, hist, enet_w, enet_b, root, bias, out, stats);
    final_kernel<<<(N_NODES * 4 + 255) / 256, 256, 0, stream>>>(
        out, stats, gamma, beta);
}